// Round 6
// baseline (489.695 us; speedup 1.0000x reference)
//
#include <hip/hip_runtime.h>
#include <hip/hip_bf16.h>
#include <math.h>

// SelfAttentionLayer: B=8,S=2048,D=1024 (fp32 interface).
// R10: 256x256 8-phase GEMM (T2+T3+T4+T5 stack). R6/R7/R9 all plateaued at
//   59-64us / MfmaUtil 21-23% -- the 2-phase structure ceiling (m233: stage+
//   vmcnt+barrier ~72% of critical path; T2/T5 null at 2ph, pay at 8ph).
//   New gemm_f8: BM=BN=256, BK=64, 512 thr = 8 waves (2Mx4N), per-wave
//   128x64 C = 8x mfma_scale_32x32x64 per K-tile (acc 128 VGPR, ~190 total,
//   2 waves/SIMD; NO min-waves bound -- R8 spill lesson). 4 phases/K-tile:
//   {issue 1 stage load || ds_read A-quadrant (+B at ph0)} -> barrier ->
//   lgkmcnt(0) -> setprio(1) -> 2 MFMA -> setprio(0) -> barrier. 3 stages x
//   32KB LDS, depth-2 prefetch, counted vmcnt(4) once per tile (never 0 in
//   steady state). Waves 0-3 stage A, 4-7 stage B (role split for T5).
//   Paired-row LDS swizzle (verified R6-R9): 128B line l holds rows {l,l+128}
//   (chunks 0-3 / 4-7), slot = chunk ^ (line&7) -> 8 dwords/bank per b128.
//   Hazards: stage t drained by vmcnt(4)+barrier at end of tile t-1 (FIFO);
//   buffer (t+2)%3 == (t-1)%3 rewritten only after issue, which follows the
//   end-of-(t-1) barrier, by which point all waves' reads are lgkm-drained
//   (per-phase lgkmcnt(0) precedes each MFMA cluster).
//   Also: 4 weight casts merged into one kernel (14 -> 11 dispatches).
// Numerics identical to R5-R9: MX-fp8 e4m3 unit scales, P x256, AO x16,
//   residual+LN fp32, preLN bf16. Kept: XCD chunk swizzle (all grids %8==0).

typedef __bf16 bf16;
typedef unsigned char u8;
typedef __attribute__((ext_vector_type(8))) __bf16 bf16x8;
typedef __attribute__((ext_vector_type(4))) __bf16 bf16x4;
typedef __attribute__((ext_vector_type(8))) int i32x8;
typedef __attribute__((ext_vector_type(16))) float f32x16;

__device__ __forceinline__ void async16(const u8* g, u8* l) {
    __builtin_amdgcn_global_load_lds(
        (const __attribute__((address_space(1))) void*)g,
        (__attribute__((address_space(3))) void*)l, 16, 0, 0);
}

// s_waitcnt imm: bits[3:0] vmcnt, [6:4] expcnt, [11:8] lgkmcnt
#define WAITCNT_VM(n) __builtin_amdgcn_s_waitcnt((15 << 8) | (7 << 4) | (n))

__device__ __forceinline__ u8 to_fp8(float v) {
    return (u8)(__builtin_amdgcn_cvt_pk_fp8_f32(v, v, 0, 0) & 0xFF);
}

__global__ __launch_bounds__(256) void cast_f32_fp8(
    const float* __restrict__ in, u8* __restrict__ out, int n)
{
    int i = (blockIdx.x * 256 + threadIdx.x) * 8;
    if (i >= n) return;
    float4 a = *(const float4*)(in + i);
    float4 b = *(const float4*)(in + i + 4);
    int lo = __builtin_amdgcn_cvt_pk_fp8_f32(a.x, a.y, 0, 0);
    lo = __builtin_amdgcn_cvt_pk_fp8_f32(a.z, a.w, lo, 1);
    int hi = __builtin_amdgcn_cvt_pk_fp8_f32(b.x, b.y, 0, 0);
    hi = __builtin_amdgcn_cvt_pk_fp8_f32(b.z, b.w, hi, 1);
    int2 o = { lo, hi };
    *(int2*)(out + i) = o;
}

// all four 1M-element weight casts in one launch; outs contiguous at out.
__global__ __launch_bounds__(256) void cast_w4(
    const float* __restrict__ W0, const float* __restrict__ W1,
    const float* __restrict__ W2, const float* __restrict__ W3,
    u8* __restrict__ out)
{
    const int b = blockIdx.x;                 // 0..2047
    const int wsel = b >> 9;                  // 512 blocks per weight
    const float* src = (wsel == 0) ? W0 : (wsel == 1) ? W1
                     : (wsel == 2) ? W2 : W3;
    const int i = ((b & 511) * 256 + threadIdx.x) * 8;
    float4 a = *(const float4*)(src + i);
    float4 c = *(const float4*)(src + i + 4);
    int lo = __builtin_amdgcn_cvt_pk_fp8_f32(a.x, a.y, 0, 0);
    lo = __builtin_amdgcn_cvt_pk_fp8_f32(a.z, a.w, lo, 1);
    int hi = __builtin_amdgcn_cvt_pk_fp8_f32(c.x, c.y, 0, 0);
    hi = __builtin_amdgcn_cvt_pk_fp8_f32(c.z, c.w, hi, 1);
    int2 o = { lo, hi };
    *(int2*)(out + (size_t)wsel * 1048576 + i) = o;
}

// C[m,n] = scale * sum_k A[m,k]*B[n,k] (+bias); A:[M,K] lda, B:[N,K] ldb, fp8.
// bias_mode: 0 none, 1 bias[n], 2 bias[m]. c_mode: 0 bf16 out, 1 fp8 out.
// grid (N/256, M/256, batch), 512 thr = 8 waves (2Mx4N), wave = 128x64 C.
// K multiple of 64, K/64 >= 3.
__global__ __launch_bounds__(512) void gemm_f8(
    const u8* __restrict__ A, long lda, long sA,
    const u8* __restrict__ B, long ldb, long sB,
    void* __restrict__ Cv, long ldc, long sC,
    const float* __restrict__ bias, int bias_mode,
    float scale, int c_mode, int K)
{
    // 3 stages x 32KB. Stage: A 16KB (128 lines x 128B) | B 16KB.
    // Line l holds rows {l, l+128}: chunks 0-3 = row l k-bytes [0,64),
    // chunks 4-7 = row l+128. Slot for (line, chunk): pos = chunk ^ (line&7).
    __shared__ u8 lds[3][32768];

    // XCD chunk swizzle (all grids used are multiples of 8 blocks).
    const int gx = gridDim.x, gy = gridDim.y;
    const int slice = gx * gy;
    const int total = slice * gridDim.z;
    int flat = ((int)blockIdx.z * gy + (int)blockIdx.y) * gx + (int)blockIdx.x;
    if ((total & 7) == 0)
        flat = (flat & 7) * (total >> 3) + (flat >> 3);
    const int bz = flat / slice;
    const int rem = flat - bz * slice;
    const int by = rem / gx;
    const int bx = rem - by * gx;

    const int tid = threadIdx.x;
    const long tM = (long)by * 256;
    const long tN = (long)bx * 256;
    A += (long)bz * sA;
    B += (long)bz * sB;

    // staging roles: waves 0-3 (tid<256) stage A, waves 4-7 stage B.
    // Thread role-local id s: slot j (j=0..3) = LDS chunk-slot s + j*256,
    // i.e. line = (s>>3) + j*32, pos = s&7, chunk = pos ^ (line&7) (line&7
    // invariant in j). Global row = line + 128*(chunk>=4); dest lane-linear
    // s*16 + j*4096 (+16384 for B) as global_load_lds requires.
    const int s = tid & 255;
    const int line0 = s >> 3;                     // 0..31
    const int sch = (s & 7) ^ (line0 & 7);
    const int skb = (sch & 3) << 4;               // k-byte within 64B row
    const int srofs = (sch & 4) ? 128 : 0;        // +128 rows if chunk >= 4
    const u8* gsrc;
    long gstr;
    if (tid < 256) { gsrc = A + (tM + line0 + srofs) * lda + skb; gstr = lda; }
    else           { gsrc = B + (tN + line0 + srofs) * ldb + skb; gstr = ldb; }
    const int dbase = ((tid < 256) ? 0 : 16384) + s * 16;

    const int w = tid >> 6, lane = tid & 63;
    const int wr = w >> 2, wc = w & 3;            // wave tile: 2M x 4N
    const int r32 = lane & 31, kh = lane >> 5;    // kh: which 32-byte K-half
    const int xr = r32 & 7;

    // fragment LDS offsets. A quadrant q: row = wr*128 + q*32 + r32 ->
    // line = q*32 + r32, chunk base cbA = wr*4 (rows >=128 in high chunks).
    // B frag n: col = wc*64 + n*32 + r32 -> line = (wc&1)*64 + n*32 + r32,
    // cbB = (wc>>1)*4. K-half kh -> chunks cb + 2kh + {0,1}.
    int oA[4][2], oB[2][2];
    const int cbA = wr * 4;
    const int cbB = (wc >> 1) * 4;
#pragma unroll
    for (int q = 0; q < 4; q++) {
        const int lineA = q * 32 + r32;
        oA[q][0] = lineA * 128 + (((cbA + 2 * kh + 0) ^ xr) << 4);
        oA[q][1] = lineA * 128 + (((cbA + 2 * kh + 1) ^ xr) << 4);
    }
#pragma unroll
    for (int n = 0; n < 2; n++) {
        const int lineB = (wc & 1) * 64 + n * 32 + r32;
        oB[n][0] = 16384 + lineB * 128 + (((cbB + 2 * kh + 0) ^ xr) << 4);
        oB[n][1] = 16384 + lineB * 128 + (((cbB + 2 * kh + 1) ^ xr) << 4);
    }

    f32x16 acc[4][2] = {};

    const int T = K >> 6;

    // prologue: stages 0,1 (4 loads per wave each -> 8 outstanding/wave),
    // drain stage 0 (vmcnt(4), FIFO) + barrier before first read.
#pragma unroll
    for (int j = 0; j < 4; j++)
        async16(gsrc + (long)j * 32 * gstr, &lds[0][dbase + j * 4096]);
#pragma unroll
    for (int j = 0; j < 4; j++)
        async16(gsrc + 64 + (long)j * 32 * gstr, &lds[1][dbase + j * 4096]);
    WAITCNT_VM(4);
    __builtin_amdgcn_s_barrier();

    union F { i32x8 v; int4 q2[2]; };

    int cur = 0;
    for (int t = 0; t < T; ++t) {
        const u8* cb = lds[cur];
        int nb = cur + 2; if (nb >= 3) nb -= 3;
        u8* pn = lds[nb];
        const long ko = (long)(t + 2) << 6;
        const bool pf = (t + 2 < T);

        F b0, b1;
#pragma unroll
        for (int q = 0; q < 4; q++) {
            // phase q: issue one prefetch slot, read this phase's fragments.
            if (pf) async16(gsrc + ko + (long)q * 32 * gstr,
                            pn + dbase + q * 4096);
            F aq;
            aq.q2[0] = *(const int4*)&cb[oA[q][0]];
            aq.q2[1] = *(const int4*)&cb[oA[q][1]];
            if (q == 0) {
                b0.q2[0] = *(const int4*)&cb[oB[0][0]];
                b0.q2[1] = *(const int4*)&cb[oB[0][1]];
                b1.q2[0] = *(const int4*)&cb[oB[1][0]];
                b1.q2[1] = *(const int4*)&cb[oB[1][1]];
            }
            __builtin_amdgcn_s_barrier();
            asm volatile("s_waitcnt lgkmcnt(0)" ::: "memory");
            __builtin_amdgcn_s_setprio(1);
            // fmt 0 = OCP fp8 e4m3; scales 0x7F (=2^0), opsel 0
            acc[q][0] = __builtin_amdgcn_mfma_scale_f32_32x32x64_f8f6f4(
                aq.v, b0.v, acc[q][0], 0, 0, 0, 0x7F7F7F7F, 0, 0x7F7F7F7F);
            acc[q][1] = __builtin_amdgcn_mfma_scale_f32_32x32x64_f8f6f4(
                aq.v, b1.v, acc[q][1], 0, 0, 0, 0x7F7F7F7F, 0, 0x7F7F7F7F);
            __builtin_amdgcn_s_setprio(0);
            if (q == 3) {
                // counted vmcnt once per tile: drain stage t+1 (keep t+2's
                // 4 in flight); 0 only at the last prefetched stage.
                if (pf) WAITCNT_VM(4);
                else if (t + 1 < T) WAITCNT_VM(0);
            }
            __builtin_amdgcn_s_barrier();
        }

        if (++cur >= 3) cur = 0;
    }

    // epilogue: 32x32 C/D layout col=lane&31, row=(reg&3)+8*(reg>>2)+4*kh
    // [m74/m101; dtype-independent m121-128]
#pragma unroll
    for (int q = 0; q < 4; q++) {
#pragma unroll
        for (int n = 0; n < 2; n++) {
            const long gn = tN + wc * 64 + n * 32 + r32;
            const float bn = (bias_mode == 1) ? bias[gn] : 0.0f;
#pragma unroll
            for (int reg = 0; reg < 16; reg++) {
                const int rowf = (reg & 3) + 8 * (reg >> 2) + 4 * kh;
                const long gm = tM + wr * 128 + q * 32 + rowf;
                float v = acc[q][n][reg] * scale + bn;
                if (bias_mode == 2) v += bias[gm];
                if (c_mode == 0)
                    ((bf16*)Cv + (long)bz * sC)[gm * ldc + gn] = (bf16)v;
                else
                    ((u8*)Cv + (long)bz * sC)[gm * ldc + gn] = to_fp8(v);
            }
        }
    }
}

// softmax over rows of 2048 bf16 scores -> fp8 P scaled x256
__global__ __launch_bounds__(256) void softmax_f8(
    const bf16* __restrict__ S, u8* __restrict__ P)
{
    const long row = blockIdx.x;
    const bf16* p = S + row * 2048;
    const int t = threadIdx.x;

    bf16x8 v = *(const bf16x8*)(p + t * 8);
    float f[8];
    float m = -3.0e38f;
#pragma unroll
    for (int i = 0; i < 8; i++) { f[i] = (float)v[i]; m = fmaxf(m, f[i]); }
    for (int o = 32; o; o >>= 1) m = fmaxf(m, __shfl_down(m, o));

    __shared__ float sm[4], ssum[4];
    if ((t & 63) == 0) sm[t >> 6] = m;
    __syncthreads();
    m = fmaxf(fmaxf(sm[0], sm[1]), fmaxf(sm[2], sm[3]));

    float s = 0.0f;
#pragma unroll
    for (int i = 0; i < 8; i++) { f[i] = __expf(f[i] - m); s += f[i]; }
    for (int o = 32; o; o >>= 1) s += __shfl_down(s, o);
    if ((t & 63) == 0) ssum[t >> 6] = s;
    __syncthreads();
    s = ssum[0] + ssum[1] + ssum[2] + ssum[3];

    const float c = 256.0f / s;   // x256: keep P out of fp8 subnormal range
    int lo = __builtin_amdgcn_cvt_pk_fp8_f32(f[0] * c, f[1] * c, 0, 0);
    lo = __builtin_amdgcn_cvt_pk_fp8_f32(f[2] * c, f[3] * c, lo, 1);
    int hi = __builtin_amdgcn_cvt_pk_fp8_f32(f[4] * c, f[5] * c, 0, 0);
    hi = __builtin_amdgcn_cvt_pk_fp8_f32(f[6] * c, f[7] * c, hi, 1);
    int2 o = { lo, hi };
    *(int2*)(P + row * 2048 + t * 8) = o;
}

// out = LN(pre + x) * gamma + beta; pre bf16, x fp32; rows of 1024
__global__ __launch_bounds__(256) void ln_res(
    const bf16* __restrict__ pre, const float* __restrict__ x,
    const float* __restrict__ gamma, const float* __restrict__ beta,
    float* __restrict__ out)
{
    const long row = blockIdx.x;
    const int t = threadIdx.x;
    const long base = row * 1024 + t * 4;

    bf16x4 a = *(const bf16x4*)(pre + base);
    float4 b = *(const float4*)(x + base);
    float v0 = (float)a[0] + b.x, v1 = (float)a[1] + b.y;
    float v2 = (float)a[2] + b.z, v3 = (float)a[3] + b.w;

    float s = v0 + v1 + v2 + v3;
    float q = v0 * v0 + v1 * v1 + v2 * v2 + v3 * v3;
    for (int o = 32; o; o >>= 1) { s += __shfl_down(s, o); q += __shfl_down(q, o); }

    __shared__ float ls[4], lq[4];
    if ((t & 63) == 0) { ls[t >> 6] = s; lq[t >> 6] = q; }
    __syncthreads();
    s = ls[0] + ls[1] + ls[2] + ls[3];
    q = lq[0] + lq[1] + lq[2] + lq[3];

    const float mean = s * (1.0f / 1024.0f);
    const float var = q * (1.0f / 1024.0f) - mean * mean;
    const float rstd = rsqrtf(var + 1e-5f);

    const int c = t * 4;
    float4 g = *(const float4*)(gamma + c);
    float4 be = *(const float4*)(beta + c);
    float4 o;
    o.x = (v0 - mean) * rstd * g.x + be.x;
    o.y = (v1 - mean) * rstd * g.y + be.y;
    o.z = (v2 - mean) * rstd * g.z + be.z;
    o.w = (v3 - mean) * rstd * g.w + be.w;
    *(float4*)(out + base) = o;
}

extern "C" void kernel_launch(void* const* d_in, const int* in_sizes, int n_in,
                              void* d_out, int out_size, void* d_ws, size_t ws_size,
                              hipStream_t stream)
{
    const float* x     = (const float*)d_in[0];
    const float* Wq    = (const float*)d_in[1];
    const float* bq    = (const float*)d_in[2];
    const float* Wk    = (const float*)d_in[3];
    const float* bk    = (const float*)d_in[4];
    const float* Wv    = (const float*)d_in[5];
    const float* bv    = (const float*)d_in[6];
    const float* Wo    = (const float*)d_in[7];
    const float* bo    = (const float*)d_in[8];
    const float* gamma = (const float*)d_in[9];
    const float* beta  = (const float*)d_in[10];
    float* out = (float*)d_out;

    char* ws = (char*)d_ws;
    u8* x8  = (u8*)(ws + (size_t)0);          // 16 MB [16384,1024]
    u8* Q8  = (u8*)(ws + (size_t)16777216);   // 16 MB (reused as AO8)
    u8* K8  = (u8*)(ws + (size_t)33554432);   // 16 MB
    u8* VT8 = (u8*)(ws + (size_t)50331648);   // 16 MB [1024,16384]
    u8* P8  = (u8*)(ws + (size_t)67108864);   // 32 MB [8,2048,2048]
    bf16* Sb = (bf16*)(ws + (size_t)104857600); // 64 MB scores; preLN reuse
    u8* Wq8 = (u8*)(ws + (size_t)176160768);  // 4 MB contiguous W{q,k,v,o}8

    // casts
    cast_f32_fp8<<<8192, 256, 0, stream>>>(x, x8, 16777216);
    cast_w4<<<2048, 256, 0, stream>>>(Wq, Wk, Wv, Wo, Wq8);
    u8* Wk8 = Wq8 + 1048576;
    u8* Wv8 = Wk8 + 1048576;
    u8* Wo8 = Wv8 + 1048576;

    // Q8 = x8@Wq8^T + bq  (fp8 out)
    gemm_f8<<<dim3(4, 64, 1), 512, 0, stream>>>(
        x8, 1024, 0, Wq8, 1024, 0, (void*)Q8, 1024, 0, bq, 1, 1.0f, 1, 1024);
    // K8
    gemm_f8<<<dim3(4, 64, 1), 512, 0, stream>>>(
        x8, 1024, 0, Wk8, 1024, 0, (void*)K8, 1024, 0, bk, 1, 1.0f, 1, 1024);
    // VT8 = Wv8@x8^T + bv(row)  [1024,16384] fp8
    gemm_f8<<<dim3(64, 4, 1), 512, 0, stream>>>(
        Wv8, 1024, 0, x8, 1024, 0, (void*)VT8, 16384, 0, bv, 2, 1.0f, 1, 1024);
    // scores (bf16) = Q8@K8^T / 32, per batch
    gemm_f8<<<dim3(8, 8, 8), 512, 0, stream>>>(
        Q8, 1024, 2097152, K8, 1024, 2097152, (void*)Sb, 2048, 4194304,
        nullptr, 0, 0.03125f, 0, 1024);
    // P8 = softmax(scores) * 256  (fp8)
    softmax_f8<<<16384, 256, 0, stream>>>(Sb, P8);
    // AO8 = (P8@VT8^T) * 16/256  -> stored AO = 16*AO_true (into Q8)
    gemm_f8<<<dim3(4, 8, 8), 512, 0, stream>>>(
        P8, 2048, 4194304, VT8, 16384, 2048, (void*)Q8, 1024, 2097152,
        nullptr, 0, 0.0625f, 1, 2048);
    // preLN (bf16, into Sb) = AO8@Wo8^T * (1/16) + bo
    gemm_f8<<<dim3(4, 64, 1), 512, 0, stream>>>(
        Q8, 1024, 0, Wo8, 1024, 0, (void*)Sb, 1024, 0, bo, 1, 0.0625f, 0, 1024);
    // out = LN(pre + x)
    ln_res<<<16384, 256, 0, stream>>>((const bf16*)Sb, x, gamma, beta, out);
}

// Round 7
// 397.895 us; speedup vs baseline: 1.2307x; 1.2307x over previous
//
#include <hip/hip_runtime.h>
#include <hip/hip_bf16.h>
#include <math.h>

// SelfAttentionLayer: B=8,S=2048,D=1024 (fp32 interface).
// R11: R10's 8-phase port had 2 MFMA/phase (~138 SIMD-cyc) between barrier
//   pairs vs the m201 template's 16 MFMA (~310 cyc) -> sync-dominated, 80us,
//   MfmaUtil 16%. Fix: 2 phases per K-tile, 4 MFMA each (~276 cyc, matches
//   template fatness), 4 barriers/K-tile (was 8). Phase = {ds_read frags ||
//   issue 2 stage loads -> barrier -> lgkmcnt(0)+sched_barrier (rule18) ->
//   setprio(1) -> 4 MFMA -> setprio(0) -> [vmcnt(4) at tile end] -> barrier}.
//   Counted vmcnt once per K-tile: drains stage t+1, keeps t+2's 4 loads in
//   flight across barriers (T4). Kept from R10 (verified): 256x256 tile,
//   512 thr = 8 waves (2Mx4N), wave C = 128x64 (8x mfma_scale_32x32x64),
//   3 stages x 32KB LDS, role-split staging (waves 0-3 A, 4-7 B), paired-row
//   swizzle (128B line l = rows {l,l+128}, slot = chunk^(line&7), 8 dw/bank),
//   XCD chunk swizzle, merged weight casts. R10 evidence the machinery works:
//   FETCH 33->24.7MB, conflicts structural, numerics pass.
// Numerics identical to R5-R10: MX-fp8 e4m3 unit scales, P x256, AO x16,
//   residual+LN fp32, preLN bf16.

typedef __bf16 bf16;
typedef unsigned char u8;
typedef __attribute__((ext_vector_type(8))) __bf16 bf16x8;
typedef __attribute__((ext_vector_type(4))) __bf16 bf16x4;
typedef __attribute__((ext_vector_type(8))) int i32x8;
typedef __attribute__((ext_vector_type(16))) float f32x16;

__device__ __forceinline__ void async16(const u8* g, u8* l) {
    __builtin_amdgcn_global_load_lds(
        (const __attribute__((address_space(1))) void*)g,
        (__attribute__((address_space(3))) void*)l, 16, 0, 0);
}

// s_waitcnt imm: bits[3:0] vmcnt, [6:4] expcnt, [11:8] lgkmcnt
#define WAITCNT_VM(n) __builtin_amdgcn_s_waitcnt((15 << 8) | (7 << 4) | (n))

__device__ __forceinline__ u8 to_fp8(float v) {
    return (u8)(__builtin_amdgcn_cvt_pk_fp8_f32(v, v, 0, 0) & 0xFF);
}

__global__ __launch_bounds__(256) void cast_f32_fp8(
    const float* __restrict__ in, u8* __restrict__ out, int n)
{
    int i = (blockIdx.x * 256 + threadIdx.x) * 8;
    if (i >= n) return;
    float4 a = *(const float4*)(in + i);
    float4 b = *(const float4*)(in + i + 4);
    int lo = __builtin_amdgcn_cvt_pk_fp8_f32(a.x, a.y, 0, 0);
    lo = __builtin_amdgcn_cvt_pk_fp8_f32(a.z, a.w, lo, 1);
    int hi = __builtin_amdgcn_cvt_pk_fp8_f32(b.x, b.y, 0, 0);
    hi = __builtin_amdgcn_cvt_pk_fp8_f32(b.z, b.w, hi, 1);
    int2 o = { lo, hi };
    *(int2*)(out + i) = o;
}

// all four 1M-element weight casts in one launch; outs contiguous at out.
__global__ __launch_bounds__(256) void cast_w4(
    const float* __restrict__ W0, const float* __restrict__ W1,
    const float* __restrict__ W2, const float* __restrict__ W3,
    u8* __restrict__ out)
{
    const int b = blockIdx.x;                 // 0..2047
    const int wsel = b >> 9;                  // 512 blocks per weight
    const float* src = (wsel == 0) ? W0 : (wsel == 1) ? W1
                     : (wsel == 2) ? W2 : W3;
    const int i = ((b & 511) * 256 + threadIdx.x) * 8;
    float4 a = *(const float4*)(src + i);
    float4 c = *(const float4*)(src + i + 4);
    int lo = __builtin_amdgcn_cvt_pk_fp8_f32(a.x, a.y, 0, 0);
    lo = __builtin_amdgcn_cvt_pk_fp8_f32(a.z, a.w, lo, 1);
    int hi = __builtin_amdgcn_cvt_pk_fp8_f32(c.x, c.y, 0, 0);
    hi = __builtin_amdgcn_cvt_pk_fp8_f32(c.z, c.w, hi, 1);
    int2 o = { lo, hi };
    *(int2*)(out + (size_t)wsel * 1048576 + i) = o;
}

// C[m,n] = scale * sum_k A[m,k]*B[n,k] (+bias); A:[M,K] lda, B:[N,K] ldb, fp8.
// bias_mode: 0 none, 1 bias[n], 2 bias[m]. c_mode: 0 bf16 out, 1 fp8 out.
// grid (N/256, M/256, batch), 512 thr = 8 waves (2Mx4N), wave = 128x64 C.
// K multiple of 64, K/64 >= 3.
__global__ __launch_bounds__(512) void gemm_f8(
    const u8* __restrict__ A, long lda, long sA,
    const u8* __restrict__ B, long ldb, long sB,
    void* __restrict__ Cv, long ldc, long sC,
    const float* __restrict__ bias, int bias_mode,
    float scale, int c_mode, int K)
{
    // 3 stages x 32KB. Stage: A 16KB (128 lines x 128B) | B 16KB.
    // Line l holds rows {l, l+128}: chunks 0-3 = row l k-bytes [0,64),
    // chunks 4-7 = row l+128. Slot for (line, chunk): pos = chunk ^ (line&7).
    __shared__ u8 lds[3][32768];

    // XCD chunk swizzle (all grids used are multiples of 8 blocks).
    const int gx = gridDim.x, gy = gridDim.y;
    const int slice = gx * gy;
    const int total = slice * gridDim.z;
    int flat = ((int)blockIdx.z * gy + (int)blockIdx.y) * gx + (int)blockIdx.x;
    if ((total & 7) == 0)
        flat = (flat & 7) * (total >> 3) + (flat >> 3);
    const int bz = flat / slice;
    const int rem = flat - bz * slice;
    const int by = rem / gx;
    const int bx = rem - by * gx;

    const int tid = threadIdx.x;
    const long tM = (long)by * 256;
    const long tN = (long)bx * 256;
    A += (long)bz * sA;
    B += (long)bz * sB;

    // staging roles: waves 0-3 (tid<256) stage A, waves 4-7 stage B.
    // Thread role-local id s: slot j (j=0..3) = LDS chunk-slot s + j*256,
    // i.e. line = (s>>3) + j*32, pos = s&7, chunk = pos ^ (line&7) (line&7
    // invariant in j). Global row = line + 128*(chunk>=4); dest lane-linear
    // s*16 + j*4096 (+16384 for B) as global_load_lds requires.
    const int s = tid & 255;
    const int line0 = s >> 3;                     // 0..31
    const int sch = (s & 7) ^ (line0 & 7);
    const int skb = (sch & 3) << 4;               // k-byte within 64B row
    const int srofs = (sch & 4) ? 128 : 0;        // +128 rows if chunk >= 4
    const u8* gsrc;
    long gstr;
    if (tid < 256) { gsrc = A + (tM + line0 + srofs) * lda + skb; gstr = lda; }
    else           { gsrc = B + (tN + line0 + srofs) * ldb + skb; gstr = ldb; }
    const int dbase = ((tid < 256) ? 0 : 16384) + s * 16;

    const int w = tid >> 6, lane = tid & 63;
    const int wr = w >> 2, wc = w & 3;            // wave tile: 2M x 4N
    const int r32 = lane & 31, kh = lane >> 5;    // kh: which 32-byte K-half
    const int xr = r32 & 7;

    // fragment LDS offsets. A quadrant q: row = wr*128 + q*32 + r32 ->
    // line = q*32 + r32, chunk base cbA = wr*4 (rows >=128 in high chunks).
    // B frag n: col = wc*64 + n*32 + r32 -> line = (wc&1)*64 + n*32 + r32,
    // cbB = (wc>>1)*4. K-half kh -> chunks cb + 2kh + {0,1}.
    int oA[4][2], oB[2][2];
    const int cbA = wr * 4;
    const int cbB = (wc >> 1) * 4;
#pragma unroll
    for (int q = 0; q < 4; q++) {
        const int lineA = q * 32 + r32;
        oA[q][0] = lineA * 128 + (((cbA + 2 * kh + 0) ^ xr) << 4);
        oA[q][1] = lineA * 128 + (((cbA + 2 * kh + 1) ^ xr) << 4);
    }
#pragma unroll
    for (int n = 0; n < 2; n++) {
        const int lineB = (wc & 1) * 64 + n * 32 + r32;
        oB[n][0] = 16384 + lineB * 128 + (((cbB + 2 * kh + 0) ^ xr) << 4);
        oB[n][1] = 16384 + lineB * 128 + (((cbB + 2 * kh + 1) ^ xr) << 4);
    }

    f32x16 acc[4][2] = {};

    const int T = K >> 6;

    // prologue: stages 0,1 (4 loads per wave each -> 8 outstanding/wave),
    // drain stage 0 (vmcnt(4), FIFO) + barrier before first read.
#pragma unroll
    for (int j = 0; j < 4; j++)
        async16(gsrc + (long)j * 32 * gstr, &lds[0][dbase + j * 4096]);
#pragma unroll
    for (int j = 0; j < 4; j++)
        async16(gsrc + 64 + (long)j * 32 * gstr, &lds[1][dbase + j * 4096]);
    WAITCNT_VM(4);
    __builtin_amdgcn_s_barrier();

    union F { i32x8 v; int4 q2[2]; };

    int cur = 0;
    for (int t = 0; t < T; ++t) {
        const u8* cb = lds[cur];
        int nb = cur + 2; if (nb >= 3) nb -= 3;
        u8* pn = lds[nb];
        const long ko = (long)(t + 2) << 6;
        const bool pf = (t + 2 < T);

        // ---- phase 0: A quadrants 0,1 + both B frags; 2 stage loads ----
        F a0, a1, b0, b1;
        a0.q2[0] = *(const int4*)&cb[oA[0][0]];
        a0.q2[1] = *(const int4*)&cb[oA[0][1]];
        a1.q2[0] = *(const int4*)&cb[oA[1][0]];
        a1.q2[1] = *(const int4*)&cb[oA[1][1]];
        b0.q2[0] = *(const int4*)&cb[oB[0][0]];
        b0.q2[1] = *(const int4*)&cb[oB[0][1]];
        b1.q2[0] = *(const int4*)&cb[oB[1][0]];
        b1.q2[1] = *(const int4*)&cb[oB[1][1]];
        if (pf) {
            async16(gsrc + ko,                    pn + dbase);
            async16(gsrc + ko + (long)32 * gstr,  pn + dbase + 4096);
        }
        __builtin_amdgcn_s_barrier();
        asm volatile("s_waitcnt lgkmcnt(0)" ::: "memory");
        __builtin_amdgcn_sched_barrier(0);   // rule 18: pin MFMA after wait
        __builtin_amdgcn_s_setprio(1);
        // fmt 0 = OCP fp8 e4m3; scales 0x7F (=2^0), opsel 0
        acc[0][0] = __builtin_amdgcn_mfma_scale_f32_32x32x64_f8f6f4(
            a0.v, b0.v, acc[0][0], 0, 0, 0, 0x7F7F7F7F, 0, 0x7F7F7F7F);
        acc[0][1] = __builtin_amdgcn_mfma_scale_f32_32x32x64_f8f6f4(
            a0.v, b1.v, acc[0][1], 0, 0, 0, 0x7F7F7F7F, 0, 0x7F7F7F7F);
        acc[1][0] = __builtin_amdgcn_mfma_scale_f32_32x32x64_f8f6f4(
            a1.v, b0.v, acc[1][0], 0, 0, 0, 0x7F7F7F7F, 0, 0x7F7F7F7F);
        acc[1][1] = __builtin_amdgcn_mfma_scale_f32_32x32x64_f8f6f4(
            a1.v, b1.v, acc[1][1], 0, 0, 0, 0x7F7F7F7F, 0, 0x7F7F7F7F);
        __builtin_amdgcn_s_setprio(0);
        __builtin_amdgcn_s_barrier();

        // ---- phase 1: A quadrants 2,3; 2 stage loads; tile-end vmcnt ----
        F a2, a3;
        a2.q2[0] = *(const int4*)&cb[oA[2][0]];
        a2.q2[1] = *(const int4*)&cb[oA[2][1]];
        a3.q2[0] = *(const int4*)&cb[oA[3][0]];
        a3.q2[1] = *(const int4*)&cb[oA[3][1]];
        if (pf) {
            async16(gsrc + ko + (long)64 * gstr,  pn + dbase + 8192);
            async16(gsrc + ko + (long)96 * gstr,  pn + dbase + 12288);
        }
        __builtin_amdgcn_s_barrier();
        asm volatile("s_waitcnt lgkmcnt(0)" ::: "memory");
        __builtin_amdgcn_sched_barrier(0);
        __builtin_amdgcn_s_setprio(1);
        acc[2][0] = __builtin_amdgcn_mfma_scale_f32_32x32x64_f8f6f4(
            a2.v, b0.v, acc[2][0], 0, 0, 0, 0x7F7F7F7F, 0, 0x7F7F7F7F);
        acc[2][1] = __builtin_amdgcn_mfma_scale_f32_32x32x64_f8f6f4(
            a2.v, b1.v, acc[2][1], 0, 0, 0, 0x7F7F7F7F, 0, 0x7F7F7F7F);
        acc[3][0] = __builtin_amdgcn_mfma_scale_f32_32x32x64_f8f6f4(
            a3.v, b0.v, acc[3][0], 0, 0, 0, 0x7F7F7F7F, 0, 0x7F7F7F7F);
        acc[3][1] = __builtin_amdgcn_mfma_scale_f32_32x32x64_f8f6f4(
            a3.v, b1.v, acc[3][1], 0, 0, 0, 0x7F7F7F7F, 0, 0x7F7F7F7F);
        __builtin_amdgcn_s_setprio(0);
        // counted vmcnt once per K-tile (T4): outstanding = stage t+1 (4,
        // issued last tile) + stage t+2 (4, this tile) -> wait(4) drains
        // t+1, keeps t+2 in flight. Tail tiles drain to 0.
        if (pf) WAITCNT_VM(4);
        else if (t + 1 < T) WAITCNT_VM(0);
        __builtin_amdgcn_s_barrier();

        if (++cur >= 3) cur = 0;
    }

    // epilogue: 32x32 C/D layout col=lane&31, row=(reg&3)+8*(reg>>2)+4*kh
    // [m74/m101; dtype-independent m121-128]
#pragma unroll
    for (int q = 0; q < 4; q++) {
#pragma unroll
        for (int n = 0; n < 2; n++) {
            const long gn = tN + wc * 64 + n * 32 + r32;
            const float bn = (bias_mode == 1) ? bias[gn] : 0.0f;
#pragma unroll
            for (int reg = 0; reg < 16; reg++) {
                const int rowf = (reg & 3) + 8 * (reg >> 2) + 4 * kh;
                const long gm = tM + wr * 128 + q * 32 + rowf;
                float v = acc[q][n][reg] * scale + bn;
                if (bias_mode == 2) v += bias[gm];
                if (c_mode == 0)
                    ((bf16*)Cv + (long)bz * sC)[gm * ldc + gn] = (bf16)v;
                else
                    ((u8*)Cv + (long)bz * sC)[gm * ldc + gn] = to_fp8(v);
            }
        }
    }
}

// softmax over rows of 2048 bf16 scores -> fp8 P scaled x256
__global__ __launch_bounds__(256) void softmax_f8(
    const bf16* __restrict__ S, u8* __restrict__ P)
{
    const long row = blockIdx.x;
    const bf16* p = S + row * 2048;
    const int t = threadIdx.x;

    bf16x8 v = *(const bf16x8*)(p + t * 8);
    float f[8];
    float m = -3.0e38f;
#pragma unroll
    for (int i = 0; i < 8; i++) { f[i] = (float)v[i]; m = fmaxf(m, f[i]); }
    for (int o = 32; o; o >>= 1) m = fmaxf(m, __shfl_down(m, o));

    __shared__ float sm[4], ssum[4];
    if ((t & 63) == 0) sm[t >> 6] = m;
    __syncthreads();
    m = fmaxf(fmaxf(sm[0], sm[1]), fmaxf(sm[2], sm[3]));

    float s = 0.0f;
#pragma unroll
    for (int i = 0; i < 8; i++) { f[i] = __expf(f[i] - m); s += f[i]; }
    for (int o = 32; o; o >>= 1) s += __shfl_down(s, o);
    if ((t & 63) == 0) ssum[t >> 6] = s;
    __syncthreads();
    s = ssum[0] + ssum[1] + ssum[2] + ssum[3];

    const float c = 256.0f / s;   // x256: keep P out of fp8 subnormal range
    int lo = __builtin_amdgcn_cvt_pk_fp8_f32(f[0] * c, f[1] * c, 0, 0);
    lo = __builtin_amdgcn_cvt_pk_fp8_f32(f[2] * c, f[3] * c, lo, 1);
    int hi = __builtin_amdgcn_cvt_pk_fp8_f32(f[4] * c, f[5] * c, 0, 0);
    hi = __builtin_amdgcn_cvt_pk_fp8_f32(f[6] * c, f[7] * c, hi, 1);
    int2 o = { lo, hi };
    *(int2*)(P + row * 2048 + t * 8) = o;
}

// out = LN(pre + x) * gamma + beta; pre bf16, x fp32; rows of 1024
__global__ __launch_bounds__(256) void ln_res(
    const bf16* __restrict__ pre, const float* __restrict__ x,
    const float* __restrict__ gamma, const float* __restrict__ beta,
    float* __restrict__ out)
{
    const long row = blockIdx.x;
    const int t = threadIdx.x;
    const long base = row * 1024 + t * 4;

    bf16x4 a = *(const bf16x4*)(pre + base);
    float4 b = *(const float4*)(x + base);
    float v0 = (float)a[0] + b.x, v1 = (float)a[1] + b.y;
    float v2 = (float)a[2] + b.z, v3 = (float)a[3] + b.w;

    float s = v0 + v1 + v2 + v3;
    float q = v0 * v0 + v1 * v1 + v2 * v2 + v3 * v3;
    for (int o = 32; o; o >>= 1) { s += __shfl_down(s, o); q += __shfl_down(q, o); }

    __shared__ float ls[4], lq[4];
    if ((t & 63) == 0) { ls[t >> 6] = s; lq[t >> 6] = q; }
    __syncthreads();
    s = ls[0] + ls[1] + ls[2] + ls[3];
    q = lq[0] + lq[1] + lq[2] + lq[3];

    const float mean = s * (1.0f / 1024.0f);
    const float var = q * (1.0f / 1024.0f) - mean * mean;
    const float rstd = rsqrtf(var + 1e-5f);

    const int c = t * 4;
    float4 g = *(const float4*)(gamma + c);
    float4 be = *(const float4*)(beta + c);
    float4 o;
    o.x = (v0 - mean) * rstd * g.x + be.x;
    o.y = (v1 - mean) * rstd * g.y + be.y;
    o.z = (v2 - mean) * rstd * g.z + be.z;
    o.w = (v3 - mean) * rstd * g.w + be.w;
    *(float4*)(out + base) = o;
}

extern "C" void kernel_launch(void* const* d_in, const int* in_sizes, int n_in,
                              void* d_out, int out_size, void* d_ws, size_t ws_size,
                              hipStream_t stream)
{
    const float* x     = (const float*)d_in[0];
    const float* Wq    = (const float*)d_in[1];
    const float* bq    = (const float*)d_in[2];
    const float* Wk    = (const float*)d_in[3];
    const float* bk    = (const float*)d_in[4];
    const float* Wv    = (const float*)d_in[5];
    const float* bv    = (const float*)d_in[6];
    const float* Wo    = (const float*)d_in[7];
    const float* bo    = (const float*)d_in[8];
    const float* gamma = (const float*)d_in[9];
    const float* beta  = (const float*)d_in[10];
    float* out = (float*)d_out;

    char* ws = (char*)d_ws;
    u8* x8  = (u8*)(ws + (size_t)0);          // 16 MB [16384,1024]
    u8* Q8  = (u8*)(ws + (size_t)16777216);   // 16 MB (reused as AO8)
    u8* K8  = (u8*)(ws + (size_t)33554432);   // 16 MB
    u8* VT8 = (u8*)(ws + (size_t)50331648);   // 16 MB [1024,16384]
    u8* P8  = (u8*)(ws + (size_t)67108864);   // 32 MB [8,2048,2048]
    bf16* Sb = (bf16*)(ws + (size_t)104857600); // 64 MB scores; preLN reuse
    u8* Wq8 = (u8*)(ws + (size_t)176160768);  // 4 MB contiguous W{q,k,v,o}8

    // casts
    cast_f32_fp8<<<8192, 256, 0, stream>>>(x, x8, 16777216);
    cast_w4<<<2048, 256, 0, stream>>>(Wq, Wk, Wv, Wo, Wq8);
    u8* Wk8 = Wq8 + 1048576;
    u8* Wv8 = Wk8 + 1048576;
    u8* Wo8 = Wv8 + 1048576;

    // Q8 = x8@Wq8^T + bq  (fp8 out)
    gemm_f8<<<dim3(4, 64, 1), 512, 0, stream>>>(
        x8, 1024, 0, Wq8, 1024, 0, (void*)Q8, 1024, 0, bq, 1, 1.0f, 1, 1024);
    // K8
    gemm_f8<<<dim3(4, 64, 1), 512, 0, stream>>>(
        x8, 1024, 0, Wk8, 1024, 0, (void*)K8, 1024, 0, bk, 1, 1.0f, 1, 1024);
    // VT8 = Wv8@x8^T + bv(row)  [1024,16384] fp8
    gemm_f8<<<dim3(64, 4, 1), 512, 0, stream>>>(
        Wv8, 1024, 0, x8, 1024, 0, (void*)VT8, 16384, 0, bv, 2, 1.0f, 1, 1024);
    // scores (bf16) = Q8@K8^T / 32, per batch
    gemm_f8<<<dim3(8, 8, 8), 512, 0, stream>>>(
        Q8, 1024, 2097152, K8, 1024, 2097152, (void*)Sb, 2048, 4194304,
        nullptr, 0, 0.03125f, 0, 1024);
    // P8 = softmax(scores) * 256  (fp8)
    softmax_f8<<<16384, 256, 0, stream>>>(Sb, P8);
    // AO8 = (P8@VT8^T) * 16/256  -> stored AO = 16*AO_true (into Q8)
    gemm_f8<<<dim3(4, 8, 8), 512, 0, stream>>>(
        P8, 2048, 4194304, VT8, 16384, 2048, (void*)Q8, 1024, 2097152,
        nullptr, 0, 0.0625f, 1, 2048);
    // preLN (bf16, into Sb) = AO8@Wo8^T * (1/16) + bo
    gemm_f8<<<dim3(4, 64, 1), 512, 0, stream>>>(
        Q8, 1024, 0, Wo8, 1024, 0, (void*)Sb, 1024, 0, bo, 1, 0.0625f, 0, 1024);
    // out = LN(pre + x)
    ln_res<<<16384, 256, 0, stream>>>((const bf16*)Sb, x, gamma, beta, out);
}

// Round 8
// 389.578 us; speedup vs baseline: 1.2570x; 1.0214x over previous
//
#include <hip/hip_runtime.h>
#include <hip/hip_bf16.h>
#include <math.h>

// SelfAttentionLayer: B=8,S=2048,D=1024 (fp32 interface).
// R12: (a) single-barrier K-tile with SPLIT lgkm counts: issue all 12
//   ds_read_b128 (group1: a0,a1,b0,b1; group2: a2,a3) + 4 staging loads,
//   then lgkmcnt(4) -> 4 MFMA -> lgkmcnt(0) -> 4 MFMA. Group2's LDS-port
//   drain overlaps MFMA group1; ONE barrier per K-tile (R11 had 4; its
//   per-phase {barrier -> drain-with-idle-matrix-pipe -> MFMA} chain left
//   wall at 4275cyc/tile vs 1104 MFMA + 1150 port floors). sched_barrier(0)
//   pins read-group order (lgkm counting) and MFMA-after-wait (rule 18).
//   vmcnt FIFO (m135): vmcnt(4) at tile top drains exactly the oldest stage.
//   Hazards: all waves lgkm(0)-drain reads before MFMAs -> before next
//   barrier; staging at t rewrites buffer (t+2)%3=(t-1)%3 after barrier(t),
//   when all waves' t-1 reads are long drained. (b) launch fusion 11->8:
//   cast_all (x + 4 weights + bqk concat); Q&K projections merged into ONE
//   gemm (Wq8||Wk8 contiguous, out QK8 [16384,2048]; scores gemm reads it
//   with lda/ldb=2048); AO8 reuses dead x8 buffer. ~110us of inter-launch
//   gap was the #2 cost line.
//   Kept (verified R10/R11): 256x256 tile, 512thr 8 waves (2Mx4N), 3x32KB
//   LDS stages, role-split staging, paired-row swizzle (128B line l = rows
//   {l,l+128}, slot=chunk^(line&7)), XCD chunk swizzle, setprio on MFMA.
// Numerics identical to R5-R11: MX-fp8 e4m3 unit scales, P x256, AO x16,
//   residual+LN fp32, preLN bf16. absmax expected 0.03125.

typedef __bf16 bf16;
typedef unsigned char u8;
typedef __attribute__((ext_vector_type(8))) __bf16 bf16x8;
typedef __attribute__((ext_vector_type(4))) __bf16 bf16x4;
typedef __attribute__((ext_vector_type(8))) int i32x8;
typedef __attribute__((ext_vector_type(16))) float f32x16;

__device__ __forceinline__ void async16(const u8* g, u8* l) {
    __builtin_amdgcn_global_load_lds(
        (const __attribute__((address_space(1))) void*)g,
        (__attribute__((address_space(3))) void*)l, 16, 0, 0);
}

// s_waitcnt imm: bits[3:0] vmcnt, [6:4] expcnt, [11:8] lgkmcnt
#define WAITCNT_VM(n) __builtin_amdgcn_s_waitcnt((15 << 8) | (7 << 4) | (n))

__device__ __forceinline__ u8 to_fp8(float v) {
    return (u8)(__builtin_amdgcn_cvt_pk_fp8_f32(v, v, 0, 0) & 0xFF);
}

// one kernel: x cast (blocks 0..8191), 4 weight casts (8192..10239),
// bias concat bq||bk (block 10240).
__global__ __launch_bounds__(256) void cast_all(
    const float* __restrict__ x,
    const float* __restrict__ W0, const float* __restrict__ W1,
    const float* __restrict__ W2, const float* __restrict__ W3,
    const float* __restrict__ bq, const float* __restrict__ bk,
    u8* __restrict__ x8, u8* __restrict__ w8, float* __restrict__ bqk)
{
    const int b = blockIdx.x, t = threadIdx.x;
    if (b < 8192) {
        const int i = (b * 256 + t) * 8;
        float4 a = *(const float4*)(x + i);
        float4 c = *(const float4*)(x + i + 4);
        int lo = __builtin_amdgcn_cvt_pk_fp8_f32(a.x, a.y, 0, 0);
        lo = __builtin_amdgcn_cvt_pk_fp8_f32(a.z, a.w, lo, 1);
        int hi = __builtin_amdgcn_cvt_pk_fp8_f32(c.x, c.y, 0, 0);
        hi = __builtin_amdgcn_cvt_pk_fp8_f32(c.z, c.w, hi, 1);
        int2 o = { lo, hi };
        *(int2*)(x8 + i) = o;
    } else if (b < 10240) {
        const int bb = b - 8192;
        const int wsel = bb >> 9;
        const float* src = (wsel == 0) ? W0 : (wsel == 1) ? W1
                         : (wsel == 2) ? W2 : W3;
        const int i = ((bb & 511) * 256 + t) * 8;
        float4 a = *(const float4*)(src + i);
        float4 c = *(const float4*)(src + i + 4);
        int lo = __builtin_amdgcn_cvt_pk_fp8_f32(a.x, a.y, 0, 0);
        lo = __builtin_amdgcn_cvt_pk_fp8_f32(a.z, a.w, lo, 1);
        int hi = __builtin_amdgcn_cvt_pk_fp8_f32(c.x, c.y, 0, 0);
        hi = __builtin_amdgcn_cvt_pk_fp8_f32(c.z, c.w, hi, 1);
        int2 o = { lo, hi };
        *(int2*)(w8 + (size_t)wsel * 1048576 + i) = o;
    } else {
        // bqk[0..1023] = bq, bqk[1024..2047] = bk; 8 floats/thread
        const int i = t * 8;
        const float* s = (i < 1024) ? (bq + i) : (bk + i - 1024);
        float4 a = *(const float4*)s;
        float4 c = *(const float4*)(s + 4);
        *(float4*)(bqk + i) = a;
        *(float4*)(bqk + i + 4) = c;
    }
}

// C[m,n] = scale * sum_k A[m,k]*B[n,k] (+bias); A:[M,K] lda, B:[N,K] ldb, fp8.
// bias_mode: 0 none, 1 bias[n], 2 bias[m]. c_mode: 0 bf16 out, 1 fp8 out.
// grid (N/256, M/256, batch), 512 thr = 8 waves (2Mx4N), wave = 128x64 C.
// K multiple of 64, K/64 >= 3.
__global__ __launch_bounds__(512) void gemm_f8(
    const u8* __restrict__ A, long lda, long sA,
    const u8* __restrict__ B, long ldb, long sB,
    void* __restrict__ Cv, long ldc, long sC,
    const float* __restrict__ bias, int bias_mode,
    float scale, int c_mode, int K)
{
    // 3 stages x 32KB. Stage: A 16KB (128 lines x 128B) | B 16KB.
    // Line l holds rows {l, l+128}: chunks 0-3 = row l k-bytes [0,64),
    // chunks 4-7 = row l+128. Slot for (line, chunk): pos = chunk ^ (line&7).
    __shared__ u8 lds[3][32768];

    // XCD chunk swizzle (all grids used are multiples of 8 blocks).
    const int gx = gridDim.x, gy = gridDim.y;
    const int slice = gx * gy;
    const int total = slice * gridDim.z;
    int flat = ((int)blockIdx.z * gy + (int)blockIdx.y) * gx + (int)blockIdx.x;
    if ((total & 7) == 0)
        flat = (flat & 7) * (total >> 3) + (flat >> 3);
    const int bz = flat / slice;
    const int rem = flat - bz * slice;
    const int by = rem / gx;
    const int bx = rem - by * gx;

    const int tid = threadIdx.x;
    const long tM = (long)by * 256;
    const long tN = (long)bx * 256;
    A += (long)bz * sA;
    B += (long)bz * sB;

    // staging roles: waves 0-3 (tid<256) stage A, waves 4-7 stage B.
    // Thread role-local id s, slot j: line = (s>>3)+j*32, pos = s&7,
    // chunk = pos ^ (line&7). Global row = line + 128*(chunk>=4);
    // dest lane-linear s*16 + j*4096 (+16384 for B).
    const int s = tid & 255;
    const int line0 = s >> 3;                     // 0..31
    const int sch = (s & 7) ^ (line0 & 7);
    const int skb = (sch & 3) << 4;               // k-byte within 64B row
    const int srofs = (sch & 4) ? 128 : 0;        // +128 rows if chunk >= 4
    const u8* gsrc;
    long gstr;
    if (tid < 256) { gsrc = A + (tM + line0 + srofs) * lda + skb; gstr = lda; }
    else           { gsrc = B + (tN + line0 + srofs) * ldb + skb; gstr = ldb; }
    const int dbase = ((tid < 256) ? 0 : 16384) + s * 16;

    const int w = tid >> 6, lane = tid & 63;
    const int wr = w >> 2, wc = w & 3;            // wave tile: 2M x 4N
    const int r32 = lane & 31, kh = lane >> 5;    // kh: which 32-byte K-half
    const int xr = r32 & 7;

    // fragment LDS offsets (paired-row layout, see R10/R11 comments).
    int oA[4][2], oB[2][2];
    const int cbA = wr * 4;
    const int cbB = (wc >> 1) * 4;
#pragma unroll
    for (int q = 0; q < 4; q++) {
        const int lineA = q * 32 + r32;
        oA[q][0] = lineA * 128 + (((cbA + 2 * kh + 0) ^ xr) << 4);
        oA[q][1] = lineA * 128 + (((cbA + 2 * kh + 1) ^ xr) << 4);
    }
#pragma unroll
    for (int n = 0; n < 2; n++) {
        const int lineB = (wc & 1) * 64 + n * 32 + r32;
        oB[n][0] = 16384 + lineB * 128 + (((cbB + 2 * kh + 0) ^ xr) << 4);
        oB[n][1] = 16384 + lineB * 128 + (((cbB + 2 * kh + 1) ^ xr) << 4);
    }

    f32x16 acc[4][2] = {};

    const int T = K >> 6;

    // prologue: stages 0,1 (4 loads per wave each -> 8 outstanding/thread)
#pragma unroll
    for (int j = 0; j < 4; j++)
        async16(gsrc + (long)j * 32 * gstr, &lds[0][dbase + j * 4096]);
#pragma unroll
    for (int j = 0; j < 4; j++)
        async16(gsrc + 64 + (long)j * 32 * gstr, &lds[1][dbase + j * 4096]);

    union F { i32x8 v; int4 q2[2]; };

    int cur = 0;
    for (int t = 0; t < T; ++t) {
        // drain own stage-t loads (oldest 4; FIFO per m135); stage t+1 stays
        // in flight across the barrier (T4 counted vmcnt).
        if (t + 1 < T) WAITCNT_VM(4);
        else WAITCNT_VM(0);
        __builtin_amdgcn_s_barrier();
        // barrier(t): all waves drained their t-1 reads (lgkm(0) below
        // precedes loop-back) -> safe to stage into buffer (t+2)%3=(t-1)%3,
        // and buffer t is fully staged+visible for reads.

        const u8* cb = lds[cur];

        // read group 1: a0,a1,b0,b1 (8 x ds_read_b128) -- operands of MFMA
        // group 1. Pinned before group 2 so lgkmcnt(4) counts correctly.
        F a0, a1, b0, b1;
        a0.q2[0] = *(const int4*)&cb[oA[0][0]];
        a0.q2[1] = *(const int4*)&cb[oA[0][1]];
        a1.q2[0] = *(const int4*)&cb[oA[1][0]];
        a1.q2[1] = *(const int4*)&cb[oA[1][1]];
        b0.q2[0] = *(const int4*)&cb[oB[0][0]];
        b0.q2[1] = *(const int4*)&cb[oB[0][1]];
        b1.q2[0] = *(const int4*)&cb[oB[1][0]];
        b1.q2[1] = *(const int4*)&cb[oB[1][1]];
        __builtin_amdgcn_sched_barrier(0);

        // read group 2: a2,a3 (4 x b128) + staging for t+2 (vmcnt only)
        F a2, a3;
        a2.q2[0] = *(const int4*)&cb[oA[2][0]];
        a2.q2[1] = *(const int4*)&cb[oA[2][1]];
        a3.q2[0] = *(const int4*)&cb[oA[3][0]];
        a3.q2[1] = *(const int4*)&cb[oA[3][1]];
        if (t + 2 < T) {
            int nb = cur + 2; if (nb >= 3) nb -= 3;
            u8* pn = lds[nb];
            const long ko = (long)(t + 2) << 6;
#pragma unroll
            for (int j = 0; j < 4; j++)
                async16(gsrc + ko + (long)j * 32 * gstr,
                        pn + dbase + j * 4096);
        }

        // wait group 1 only (4 newest -- a2,a3 -- may stay outstanding);
        // group 2's port drain overlaps MFMA group 1.
        asm volatile("s_waitcnt lgkmcnt(4)" ::: "memory");
        __builtin_amdgcn_sched_barrier(0);   // rule 18
        __builtin_amdgcn_s_setprio(1);
        // fmt 0 = OCP fp8 e4m3; scales 0x7F (=2^0), opsel 0
        acc[0][0] = __builtin_amdgcn_mfma_scale_f32_32x32x64_f8f6f4(
            a0.v, b0.v, acc[0][0], 0, 0, 0, 0x7F7F7F7F, 0, 0x7F7F7F7F);
        acc[0][1] = __builtin_amdgcn_mfma_scale_f32_32x32x64_f8f6f4(
            a0.v, b1.v, acc[0][1], 0, 0, 0, 0x7F7F7F7F, 0, 0x7F7F7F7F);
        acc[1][0] = __builtin_amdgcn_mfma_scale_f32_32x32x64_f8f6f4(
            a1.v, b0.v, acc[1][0], 0, 0, 0, 0x7F7F7F7F, 0, 0x7F7F7F7F);
        acc[1][1] = __builtin_amdgcn_mfma_scale_f32_32x32x64_f8f6f4(
            a1.v, b1.v, acc[1][1], 0, 0, 0, 0x7F7F7F7F, 0, 0x7F7F7F7F);
        __builtin_amdgcn_s_setprio(0);

        asm volatile("s_waitcnt lgkmcnt(0)" ::: "memory");
        __builtin_amdgcn_sched_barrier(0);
        __builtin_amdgcn_s_setprio(1);
        acc[2][0] = __builtin_amdgcn_mfma_scale_f32_32x32x64_f8f6f4(
            a2.v, b0.v, acc[2][0], 0, 0, 0, 0x7F7F7F7F, 0, 0x7F7F7F7F);
        acc[2][1] = __builtin_amdgcn_mfma_scale_f32_32x32x64_f8f6f4(
            a2.v, b1.v, acc[2][1], 0, 0, 0, 0x7F7F7F7F, 0, 0x7F7F7F7F);
        acc[3][0] = __builtin_amdgcn_mfma_scale_f32_32x32x64_f8f6f4(
            a3.v, b0.v, acc[3][0], 0, 0, 0, 0x7F7F7F7F, 0, 0x7F7F7F7F);
        acc[3][1] = __builtin_amdgcn_mfma_scale_f32_32x32x64_f8f6f4(
            a3.v, b1.v, acc[3][1], 0, 0, 0, 0x7F7F7F7F, 0, 0x7F7F7F7F);
        __builtin_amdgcn_s_setprio(0);

        if (++cur >= 3) cur = 0;
    }

    // epilogue: 32x32 C/D layout col=lane&31, row=(reg&3)+8*(reg>>2)+4*kh
#pragma unroll
    for (int q = 0; q < 4; q++) {
#pragma unroll
        for (int n = 0; n < 2; n++) {
            const long gn = tN + wc * 64 + n * 32 + r32;
            const float bn = (bias_mode == 1) ? bias[gn] : 0.0f;
#pragma unroll
            for (int reg = 0; reg < 16; reg++) {
                const int rowf = (reg & 3) + 8 * (reg >> 2) + 4 * kh;
                const long gm = tM + wr * 128 + q * 32 + rowf;
                float v = acc[q][n][reg] * scale + bn;
                if (bias_mode == 2) v += bias[gm];
                if (c_mode == 0)
                    ((bf16*)Cv + (long)bz * sC)[gm * ldc + gn] = (bf16)v;
                else
                    ((u8*)Cv + (long)bz * sC)[gm * ldc + gn] = to_fp8(v);
            }
        }
    }
}

// softmax over rows of 2048 bf16 scores -> fp8 P scaled x256
__global__ __launch_bounds__(256) void softmax_f8(
    const bf16* __restrict__ S, u8* __restrict__ P)
{
    const long row = blockIdx.x;
    const bf16* p = S + row * 2048;
    const int t = threadIdx.x;

    bf16x8 v = *(const bf16x8*)(p + t * 8);
    float f[8];
    float m = -3.0e38f;
#pragma unroll
    for (int i = 0; i < 8; i++) { f[i] = (float)v[i]; m = fmaxf(m, f[i]); }
    for (int o = 32; o; o >>= 1) m = fmaxf(m, __shfl_down(m, o));

    __shared__ float sm[4], ssum[4];
    if ((t & 63) == 0) sm[t >> 6] = m;
    __syncthreads();
    m = fmaxf(fmaxf(sm[0], sm[1]), fmaxf(sm[2], sm[3]));

    float s = 0.0f;
#pragma unroll
    for (int i = 0; i < 8; i++) { f[i] = __expf(f[i] - m); s += f[i]; }
    for (int o = 32; o; o >>= 1) s += __shfl_down(s, o);
    if ((t & 63) == 0) ssum[t >> 6] = s;
    __syncthreads();
    s = ssum[0] + ssum[1] + ssum[2] + ssum[3];

    const float c = 256.0f / s;   // x256: keep P out of fp8 subnormal range
    int lo = __builtin_amdgcn_cvt_pk_fp8_f32(f[0] * c, f[1] * c, 0, 0);
    lo = __builtin_amdgcn_cvt_pk_fp8_f32(f[2] * c, f[3] * c, lo, 1);
    int hi = __builtin_amdgcn_cvt_pk_fp8_f32(f[4] * c, f[5] * c, 0, 0);
    hi = __builtin_amdgcn_cvt_pk_fp8_f32(f[6] * c, f[7] * c, hi, 1);
    int2 o = { lo, hi };
    *(int2*)(P + row * 2048 + t * 8) = o;
}

// out = LN(pre + x) * gamma + beta; pre bf16, x fp32; rows of 1024
__global__ __launch_bounds__(256) void ln_res(
    const bf16* __restrict__ pre, const float* __restrict__ x,
    const float* __restrict__ gamma, const float* __restrict__ beta,
    float* __restrict__ out)
{
    const long row = blockIdx.x;
    const int t = threadIdx.x;
    const long base = row * 1024 + t * 4;

    bf16x4 a = *(const bf16x4*)(pre + base);
    float4 b = *(const float4*)(x + base);
    float v0 = (float)a[0] + b.x, v1 = (float)a[1] + b.y;
    float v2 = (float)a[2] + b.z, v3 = (float)a[3] + b.w;

    float s = v0 + v1 + v2 + v3;
    float q = v0 * v0 + v1 * v1 + v2 * v2 + v3 * v3;
    for (int o = 32; o; o >>= 1) { s += __shfl_down(s, o); q += __shfl_down(q, o); }

    __shared__ float ls[4], lq[4];
    if ((t & 63) == 0) { ls[t >> 6] = s; lq[t >> 6] = q; }
    __syncthreads();
    s = ls[0] + ls[1] + ls[2] + ls[3];
    q = lq[0] + lq[1] + lq[2] + lq[3];

    const float mean = s * (1.0f / 1024.0f);
    const float var = q * (1.0f / 1024.0f) - mean * mean;
    const float rstd = rsqrtf(var + 1e-5f);

    const int c = t * 4;
    float4 g = *(const float4*)(gamma + c);
    float4 be = *(const float4*)(beta + c);
    float4 o;
    o.x = (v0 - mean) * rstd * g.x + be.x;
    o.y = (v1 - mean) * rstd * g.y + be.y;
    o.z = (v2 - mean) * rstd * g.z + be.z;
    o.w = (v3 - mean) * rstd * g.w + be.w;
    *(float4*)(out + base) = o;
}

extern "C" void kernel_launch(void* const* d_in, const int* in_sizes, int n_in,
                              void* d_out, int out_size, void* d_ws, size_t ws_size,
                              hipStream_t stream)
{
    const float* x     = (const float*)d_in[0];
    const float* Wq    = (const float*)d_in[1];
    const float* bq    = (const float*)d_in[2];
    const float* Wk    = (const float*)d_in[3];
    const float* bk    = (const float*)d_in[4];
    const float* Wv    = (const float*)d_in[5];
    const float* bv    = (const float*)d_in[6];
    const float* Wo    = (const float*)d_in[7];
    const float* bo    = (const float*)d_in[8];
    const float* gamma = (const float*)d_in[9];
    const float* beta  = (const float*)d_in[10];
    float* out = (float*)d_out;

    char* ws = (char*)d_ws;
    u8* x8  = (u8*)(ws + (size_t)0);          // 16 MB; reused as AO8 later
    u8* QK8 = (u8*)(ws + (size_t)16777216);   // 32 MB [16384,2048] Q||K
    u8* VT8 = (u8*)(ws + (size_t)50331648);   // 16 MB [1024,16384]
    u8* P8  = (u8*)(ws + (size_t)67108864);   // 32 MB [8,2048,2048]
    float* bqk = (float*)(ws + (size_t)100663296); // 8 KB bq||bk
    bf16* Sb = (bf16*)(ws + (size_t)104857600); // 64 MB scores; preLN reuse
    u8* Wq8 = (u8*)(ws + (size_t)176160768);  // 4 MB contiguous W{q,k,v,o}8
    u8* Wv8 = Wq8 + 2097152;
    u8* Wo8 = Wv8 + 1048576;
    u8* AO8 = x8;                              // x8 dead after projections

    // all casts + bias concat (1 launch)
    cast_all<<<10241, 256, 0, stream>>>(x, Wq, Wk, Wv, Wo, bq, bk,
                                        x8, Wq8, bqk);

    // QK8 = x8 @ [Wq8;Wk8]^T + bqk  (fp8 out, [16384,2048])
    gemm_f8<<<dim3(8, 64, 1), 512, 0, stream>>>(
        x8, 1024, 0, Wq8, 1024, 0, (void*)QK8, 2048, 0, bqk, 1, 1.0f, 1, 1024);
    // VT8 = Wv8@x8^T + bv(row)  [1024,16384] fp8
    gemm_f8<<<dim3(64, 4, 1), 512, 0, stream>>>(
        Wv8, 1024, 0, x8, 1024, 0, (void*)VT8, 16384, 0, bv, 2, 1.0f, 1, 1024);
    // scores (bf16) = Q@K^T / 32 per batch; Q = QK8[:, :1024], K = QK8[:,1024:]
    gemm_f8<<<dim3(8, 8, 8), 512, 0, stream>>>(
        QK8, 2048, 4194304, QK8 + 1024, 2048, 4194304, (void*)Sb, 2048, 4194304,
        nullptr, 0, 0.03125f, 0, 1024);
    // P8 = softmax(scores) * 256  (fp8)
    softmax_f8<<<16384, 256, 0, stream>>>(Sb, P8);
    // AO8 = (P8@VT8^T) * 16/256 -> stored AO = 16*AO_true (into x8 slot)
    gemm_f8<<<dim3(4, 8, 8), 512, 0, stream>>>(
        P8, 2048, 4194304, VT8, 16384, 2048, (void*)AO8, 1024, 2097152,
        nullptr, 0, 0.0625f, 1, 2048);
    // preLN (bf16, into Sb) = AO8@Wo8^T * (1/16) + bo
    gemm_f8<<<dim3(4, 64, 1), 512, 0, stream>>>(
        AO8, 1024, 0, Wo8, 1024, 0, (void*)Sb, 1024, 0, bo, 1, 0.0625f, 0, 1024);
    // out = LN(pre + x)
    ln_res<<<16384, 256, 0, stream>>>((const bf16*)Sb, x, gamma, beta, out);
}

// Round 9
// 388.511 us; speedup vs baseline: 1.2604x; 1.0027x over previous
//
#include <hip/hip_runtime.h>
#include <hip/hip_bf16.h>
#include <math.h>

// SelfAttentionLayer: B=8,S=2048,D=1024 (fp32 interface).
// R13: BK=128 double-pump. R12 accounting: wall 3900cyc/K-tile vs MFMA 1104 +
//   port <=1150 -> barrier lockstep alternates port/MFMA phases and ~1000cyc
//   sync; occupancy is register-capped at 2 waves/SIMD (232/256 unified) so
//   no cross-block fill. Remaining lever: amortize sync. BK=128: one barrier
//   + one vmcnt per 128 K-cols (half of R12), 16 MFMA/wave/tile in 4 lgkm
//   groups, kt1 reads issued DURING kt0 MFMA clusters (peak live operands 48,
//   same as R12 -> no spill). 2 stages x 64KB = 128KB LDS ping-pong; staging
//   (8x async16/thread) at tile top right after barrier -> full-tile latency
//   cover, vmcnt(0) at next top ~free. Hazard: stage t+1 -> buffer read at
//   t-1, drained chip-wide before barrier(t). 128B rows native: R6-verified
//   swizzle slot = chunk ^ (row&7); kt1/pair offsets as XOR deltas dk/dp.
//   Kept: 256x256 tile, 8 waves (2Mx4N), role-split staging, XCD swizzle,
//   setprio, rule-18 sched_barrier after lgkm waits, R12 launch fusion.
// Numerics identical to R5-R12: MX-fp8 e4m3 unit scales, P x256, AO x16,
//   residual+LN fp32, preLN bf16. absmax expected 0.03125.

typedef __bf16 bf16;
typedef unsigned char u8;
typedef __attribute__((ext_vector_type(8))) __bf16 bf16x8;
typedef __attribute__((ext_vector_type(4))) __bf16 bf16x4;
typedef __attribute__((ext_vector_type(8))) int i32x8;
typedef __attribute__((ext_vector_type(16))) float f32x16;

__device__ __forceinline__ void async16(const u8* g, u8* l) {
    __builtin_amdgcn_global_load_lds(
        (const __attribute__((address_space(1))) void*)g,
        (__attribute__((address_space(3))) void*)l, 16, 0, 0);
}

// s_waitcnt imm: bits[3:0] vmcnt, [6:4] expcnt, [11:8] lgkmcnt
#define WAITCNT_VM(n) __builtin_amdgcn_s_waitcnt((15 << 8) | (7 << 4) | (n))
#define LGKM(n) asm volatile("s_waitcnt lgkmcnt(" #n ")" ::: "memory")
#define SBAR() __builtin_amdgcn_sched_barrier(0)

__device__ __forceinline__ u8 to_fp8(float v) {
    return (u8)(__builtin_amdgcn_cvt_pk_fp8_f32(v, v, 0, 0) & 0xFF);
}

// one kernel: x cast (blocks 0..8191), 4 weight casts (8192..10239),
// bias concat bq||bk (block 10240).
__global__ __launch_bounds__(256) void cast_all(
    const float* __restrict__ x,
    const float* __restrict__ W0, const float* __restrict__ W1,
    const float* __restrict__ W2, const float* __restrict__ W3,
    const float* __restrict__ bq, const float* __restrict__ bk,
    u8* __restrict__ x8, u8* __restrict__ w8, float* __restrict__ bqk)
{
    const int b = blockIdx.x, t = threadIdx.x;
    if (b < 8192) {
        const int i = (b * 256 + t) * 8;
        float4 a = *(const float4*)(x + i);
        float4 c = *(const float4*)(x + i + 4);
        int lo = __builtin_amdgcn_cvt_pk_fp8_f32(a.x, a.y, 0, 0);
        lo = __builtin_amdgcn_cvt_pk_fp8_f32(a.z, a.w, lo, 1);
        int hi = __builtin_amdgcn_cvt_pk_fp8_f32(c.x, c.y, 0, 0);
        hi = __builtin_amdgcn_cvt_pk_fp8_f32(c.z, c.w, hi, 1);
        int2 o = { lo, hi };
        *(int2*)(x8 + i) = o;
    } else if (b < 10240) {
        const int bb = b - 8192;
        const int wsel = bb >> 9;
        const float* src = (wsel == 0) ? W0 : (wsel == 1) ? W1
                         : (wsel == 2) ? W2 : W3;
        const int i = ((bb & 511) * 256 + t) * 8;
        float4 a = *(const float4*)(src + i);
        float4 c = *(const float4*)(src + i + 4);
        int lo = __builtin_amdgcn_cvt_pk_fp8_f32(a.x, a.y, 0, 0);
        lo = __builtin_amdgcn_cvt_pk_fp8_f32(a.z, a.w, lo, 1);
        int hi = __builtin_amdgcn_cvt_pk_fp8_f32(c.x, c.y, 0, 0);
        hi = __builtin_amdgcn_cvt_pk_fp8_f32(c.z, c.w, hi, 1);
        int2 o = { lo, hi };
        *(int2*)(w8 + (size_t)wsel * 1048576 + i) = o;
    } else {
        const int i = t * 8;
        const float* s = (i < 1024) ? (bq + i) : (bk + i - 1024);
        float4 a = *(const float4*)s;
        float4 c = *(const float4*)(s + 4);
        *(float4*)(bqk + i) = a;
        *(float4*)(bqk + i + 4) = c;
    }
}

// C[m,n] = scale * sum_k A[m,k]*B[n,k] (+bias); A:[M,K] lda, B:[N,K] ldb, fp8.
// bias_mode: 0 none, 1 bias[n], 2 bias[m]. c_mode: 0 bf16 out, 1 fp8 out.
// grid (N/256, M/256, batch), 512 thr = 8 waves (2Mx4N), wave = 128x64 C.
// K multiple of 128, K/128 >= 2.
__global__ __launch_bounds__(512) void gemm_f8(
    const u8* __restrict__ A, long lda, long sA,
    const u8* __restrict__ B, long ldb, long sB,
    void* __restrict__ Cv, long ldc, long sC,
    const float* __restrict__ bias, int bias_mode,
    float scale, int c_mode, int K)
{
    // 2 stages x 64KB. Stage: A 32KB (256 rows x 128B) | B 32KB.
    // Row r is a native 128B line; chunk c (16B) stored at slot c ^ (r&7)
    // (R6-verified: conflict-free ds_read_b128, 8 dwords/bank).
    __shared__ u8 lds[2][65536];

    // XCD chunk swizzle (all grids used are multiples of 8 blocks).
    const int gx = gridDim.x, gy = gridDim.y;
    const int slice = gx * gy;
    const int total = slice * gridDim.z;
    int flat = ((int)blockIdx.z * gy + (int)blockIdx.y) * gx + (int)blockIdx.x;
    if ((total & 7) == 0)
        flat = (flat & 7) * (total >> 3) + (flat >> 3);
    const int bz = flat / slice;
    const int rem = flat - bz * slice;
    const int by = rem / gx;
    const int bx = rem - by * gx;

    const int tid = threadIdx.x;
    const long tM = (long)by * 256;
    const long tN = (long)bx * 256;
    A += (long)bz * sA;
    B += (long)bz * sB;

    // staging roles: waves 0-3 (tid<256) stage A, waves 4-7 stage B.
    // Thread role-local id s, load j=0..7: LDS slot = j*256 + s -> row =
    // (s>>3) + j*32, pos = s&7, chunk = pos ^ (row&7) (row&7 invariant in j).
    // Global: row, k-byte chunk*16. Dest lane-linear s*16 + j*4096
    // (+32768 for B) as global_load_lds requires.
    const int s = tid & 255;
    const int row0 = s >> 3;                      // 0..31
    const int sch = (s & 7) ^ (row0 & 7);
    const int skb = sch << 4;                     // k-byte 0..112
    const u8* gsrc;
    long gstr;
    if (tid < 256) { gsrc = A + (tM + row0) * lda + skb; gstr = lda; }
    else           { gsrc = B + (tN + row0) * ldb + skb; gstr = ldb; }
    const int dbase = ((tid < 256) ? 0 : 32768) + s * 16;

    const int w = tid >> 6, lane = tid & 63;
    const int wr = w >> 2, wc = w & 3;            // wave tile: 2M x 4N
    const int r32 = lane & 31, kh = lane >> 5;    // kh: 32-byte K-half
    const int xr = r32 & 7;

    // base fragment offsets (kt=0, pair=0, chunk 2kh). kt1: chunk +4 flips
    // bit2 -> byte delta dk = (xr&4)? -64 : +64. pair: chunk +1 flips bit0
    // -> dp = (xr&1)? -16 : +16.
    const int dk = (xr & 4) ? -64 : 64;
    const int dp = (xr & 1) ? -16 : 16;
    const int cb0 = ((2 * kh) ^ xr) << 4;
    int oA[4], oB[2];
#pragma unroll
    for (int q = 0; q < 4; q++)
        oA[q] = (wr * 128 + q * 32 + r32) * 128 + cb0;
#pragma unroll
    for (int n = 0; n < 2; n++)
        oB[n] = 32768 + (wc * 64 + n * 32 + r32) * 128 + cb0;

    f32x16 acc[4][2] = {};

    const int T = K >> 7;

    // prologue: stage 0 (8 loads/thread)
#pragma unroll
    for (int j = 0; j < 8; j++)
        async16(gsrc + (long)j * 32 * gstr, &lds[0][dbase + j * 4096]);

    union F { i32x8 v; int4 q2[2]; };

    for (int t = 0; t < T; ++t) {
        // stage-t loads were issued a full tile ago -> vmcnt(0) ~free.
        WAITCNT_VM(0);
        __builtin_amdgcn_s_barrier();

        // staging for t+1 FIRST (max latency cover). Target buffer was read
        // at tile t-1 and is chip-wide drained (all waves passed barrier(t)
        // after their lgkm(0) of t-1).
        if (t + 1 < T) {
            u8* pn = lds[(t + 1) & 1];
            const long ko = (long)(t + 1) << 7;
#pragma unroll
            for (int j = 0; j < 8; j++)
                async16(gsrc + ko + (long)j * 32 * gstr,
                        pn + dbase + j * 4096);
        }

        const u8* cb = lds[t & 1];

        // ---- kt0 reads: g1 = a0,a1,b0,b1 (8 b128); g2 = a2,a3 (4) ----
        F a0, a1, b0, b1, a2, a3;
        a0.q2[0] = *(const int4*)&cb[oA[0]];
        a0.q2[1] = *(const int4*)&cb[oA[0] + dp];
        a1.q2[0] = *(const int4*)&cb[oA[1]];
        a1.q2[1] = *(const int4*)&cb[oA[1] + dp];
        b0.q2[0] = *(const int4*)&cb[oB[0]];
        b0.q2[1] = *(const int4*)&cb[oB[0] + dp];
        b1.q2[0] = *(const int4*)&cb[oB[1]];
        b1.q2[1] = *(const int4*)&cb[oB[1] + dp];
        SBAR();
        a2.q2[0] = *(const int4*)&cb[oA[2]];
        a2.q2[1] = *(const int4*)&cb[oA[2] + dp];
        a3.q2[0] = *(const int4*)&cb[oA[3]];
        a3.q2[1] = *(const int4*)&cb[oA[3] + dp];
        SBAR();

        // fmt 0 = OCP fp8 e4m3; scales 0x7F (=2^0), opsel 0
        LGKM(4); SBAR();
        __builtin_amdgcn_s_setprio(1);
        acc[0][0] = __builtin_amdgcn_mfma_scale_f32_32x32x64_f8f6f4(
            a0.v, b0.v, acc[0][0], 0, 0, 0, 0x7F7F7F7F, 0, 0x7F7F7F7F);
        acc[0][1] = __builtin_amdgcn_mfma_scale_f32_32x32x64_f8f6f4(
            a0.v, b1.v, acc[0][1], 0, 0, 0, 0x7F7F7F7F, 0, 0x7F7F7F7F);
        acc[1][0] = __builtin_amdgcn_mfma_scale_f32_32x32x64_f8f6f4(
            a1.v, b0.v, acc[1][0], 0, 0, 0, 0x7F7F7F7F, 0, 0x7F7F7F7F);
        acc[1][1] = __builtin_amdgcn_mfma_scale_f32_32x32x64_f8f6f4(
            a1.v, b1.v, acc[1][1], 0, 0, 0, 0x7F7F7F7F, 0, 0x7F7F7F7F);
        __builtin_amdgcn_s_setprio(0);
        SBAR();

        // ---- kt1 g1 reads issue under kt0-g2 MFMA ----
        F c0, c1, d0, d1;
        c0.q2[0] = *(const int4*)&cb[oA[0] + dk];
        c0.q2[1] = *(const int4*)&cb[oA[0] + dk + dp];
        c1.q2[0] = *(const int4*)&cb[oA[1] + dk];
        c1.q2[1] = *(const int4*)&cb[oA[1] + dk + dp];
        d0.q2[0] = *(const int4*)&cb[oB[0] + dk];
        d0.q2[1] = *(const int4*)&cb[oB[0] + dk + dp];
        d1.q2[0] = *(const int4*)&cb[oB[1] + dk];
        d1.q2[1] = *(const int4*)&cb[oB[1] + dk + dp];
        SBAR();

        LGKM(8); SBAR();   // kt0-g2 (a2,a3) drained; kt1-g1 may be in flight
        __builtin_amdgcn_s_setprio(1);
        acc[2][0] = __builtin_amdgcn_mfma_scale_f32_32x32x64_f8f6f4(
            a2.v, b0.v, acc[2][0], 0, 0, 0, 0x7F7F7F7F, 0, 0x7F7F7F7F);
        acc[2][1] = __builtin_amdgcn_mfma_scale_f32_32x32x64_f8f6f4(
            a2.v, b1.v, acc[2][1], 0, 0, 0, 0x7F7F7F7F, 0, 0x7F7F7F7F);
        acc[3][0] = __builtin_amdgcn_mfma_scale_f32_32x32x64_f8f6f4(
            a3.v, b0.v, acc[3][0], 0, 0, 0, 0x7F7F7F7F, 0, 0x7F7F7F7F);
        acc[3][1] = __builtin_amdgcn_mfma_scale_f32_32x32x64_f8f6f4(
            a3.v, b1.v, acc[3][1], 0, 0, 0, 0x7F7F7F7F, 0, 0x7F7F7F7F);
        __builtin_amdgcn_s_setprio(0);
        SBAR();

        // ---- kt1 g2 reads issue under kt1-g1 MFMA ----
        F c2, c3;
        c2.q2[0] = *(const int4*)&cb[oA[2] + dk];
        c2.q2[1] = *(const int4*)&cb[oA[2] + dk + dp];
        c3.q2[0] = *(const int4*)&cb[oA[3] + dk];
        c3.q2[1] = *(const int4*)&cb[oA[3] + dk + dp];
        SBAR();

        LGKM(4); SBAR();   // kt1-g1 drained
        __builtin_amdgcn_s_setprio(1);
        acc[0][0] = __builtin_amdgcn_mfma_scale_f32_32x32x64_f8f6f4(
            c0.v, d0.v, acc[0][0], 0, 0, 0, 0x7F7F7F7F, 0, 0x7F7F7F7F);
        acc[0][1] = __builtin_amdgcn_mfma_scale_f32_32x32x64_f8f6f4(
            c0.v, d1.v, acc[0][1], 0, 0, 0, 0x7F7F7F7F, 0, 0x7F7F7F7F);
        acc[1][0] = __builtin_amdgcn_mfma_scale_f32_32x32x64_f8f6f4(
            c1.v, d0.v, acc[1][0], 0, 0, 0, 0x7F7F7F7F, 0, 0x7F7F7F7F);
        acc[1][1] = __builtin_amdgcn_mfma_scale_f32_32x32x64_f8f6f4(
            c1.v, d1.v, acc[1][1], 0, 0, 0, 0x7F7F7F7F, 0, 0x7F7F7F7F);
        __builtin_amdgcn_s_setprio(0);
        SBAR();

        LGKM(0); SBAR();   // kt1-g2 drained
        __builtin_amdgcn_s_setprio(1);
        acc[2][0] = __builtin_amdgcn_mfma_scale_f32_32x32x64_f8f6f4(
            c2.v, d0.v, acc[2][0], 0, 0, 0, 0x7F7F7F7F, 0, 0x7F7F7F7F);
        acc[2][1] = __builtin_amdgcn_mfma_scale_f32_32x32x64_f8f6f4(
            c2.v, d1.v, acc[2][1], 0, 0, 0, 0x7F7F7F7F, 0, 0x7F7F7F7F);
        acc[3][0] = __builtin_amdgcn_mfma_scale_f32_32x32x64_f8f6f4(
            c3.v, d0.v, acc[3][0], 0, 0, 0, 0x7F7F7F7F, 0, 0x7F7F7F7F);
        acc[3][1] = __builtin_amdgcn_mfma_scale_f32_32x32x64_f8f6f4(
            c3.v, d1.v, acc[3][1], 0, 0, 0, 0x7F7F7F7F, 0, 0x7F7F7F7F);
        __builtin_amdgcn_s_setprio(0);
        SBAR();
    }

    // epilogue: 32x32 C/D layout col=lane&31, row=(reg&3)+8*(reg>>2)+4*kh
#pragma unroll
    for (int q = 0; q < 4; q++) {
#pragma unroll
        for (int n = 0; n < 2; n++) {
            const long gn = tN + wc * 64 + n * 32 + r32;
            const float bn = (bias_mode == 1) ? bias[gn] : 0.0f;
#pragma unroll
            for (int reg = 0; reg < 16; reg++) {
                const int rowf = (reg & 3) + 8 * (reg >> 2) + 4 * kh;
                const long gm = tM + wr * 128 + q * 32 + rowf;
                float v = acc[q][n][reg] * scale + bn;
                if (bias_mode == 2) v += bias[gm];
                if (c_mode == 0)
                    ((bf16*)Cv + (long)bz * sC)[gm * ldc + gn] = (bf16)v;
                else
                    ((u8*)Cv + (long)bz * sC)[gm * ldc + gn] = to_fp8(v);
            }
        }
    }
}

// softmax over rows of 2048 bf16 scores -> fp8 P scaled x256
__global__ __launch_bounds__(256) void softmax_f8(
    const bf16* __restrict__ S, u8* __restrict__ P)
{
    const long row = blockIdx.x;
    const bf16* p = S + row * 2048;
    const int t = threadIdx.x;

    bf16x8 v = *(const bf16x8*)(p + t * 8);
    float f[8];
    float m = -3.0e38f;
#pragma unroll
    for (int i = 0; i < 8; i++) { f[i] = (float)v[i]; m = fmaxf(m, f[i]); }
    for (int o = 32; o; o >>= 1) m = fmaxf(m, __shfl_down(m, o));

    __shared__ float sm[4], ssum[4];
    if ((t & 63) == 0) sm[t >> 6] = m;
    __syncthreads();
    m = fmaxf(fmaxf(sm[0], sm[1]), fmaxf(sm[2], sm[3]));

    float s = 0.0f;
#pragma unroll
    for (int i = 0; i < 8; i++) { f[i] = __expf(f[i] - m); s += f[i]; }
    for (int o = 32; o; o >>= 1) s += __shfl_down(s, o);
    if ((t & 63) == 0) ssum[t >> 6] = s;
    __syncthreads();
    s = ssum[0] + ssum[1] + ssum[2] + ssum[3];

    const float c = 256.0f / s;   // x256: keep P out of fp8 subnormal range
    int lo = __builtin_amdgcn_cvt_pk_fp8_f32(f[0] * c, f[1] * c, 0, 0);
    lo = __builtin_amdgcn_cvt_pk_fp8_f32(f[2] * c, f[3] * c, lo, 1);
    int hi = __builtin_amdgcn_cvt_pk_fp8_f32(f[4] * c, f[5] * c, 0, 0);
    hi = __builtin_amdgcn_cvt_pk_fp8_f32(f[6] * c, f[7] * c, hi, 1);
    int2 o = { lo, hi };
    *(int2*)(P + row * 2048 + t * 8) = o;
}

// out = LN(pre + x) * gamma + beta; pre bf16, x fp32; rows of 1024
__global__ __launch_bounds__(256) void ln_res(
    const bf16* __restrict__ pre, const float* __restrict__ x,
    const float* __restrict__ gamma, const float* __restrict__ beta,
    float* __restrict__ out)
{
    const long row = blockIdx.x;
    const int t = threadIdx.x;
    const long base = row * 1024 + t * 4;

    bf16x4 a = *(const bf16x4*)(pre + base);
    float4 b = *(const float4*)(x + base);
    float v0 = (float)a[0] + b.x, v1 = (float)a[1] + b.y;
    float v2 = (float)a[2] + b.z, v3 = (float)a[3] + b.w;

    float s = v0 + v1 + v2 + v3;
    float q = v0 * v0 + v1 * v1 + v2 * v2 + v3 * v3;
    for (int o = 32; o; o >>= 1) { s += __shfl_down(s, o); q += __shfl_down(q, o); }

    __shared__ float ls[4], lq[4];
    if ((t & 63) == 0) { ls[t >> 6] = s; lq[t >> 6] = q; }
    __syncthreads();
    s = ls[0] + ls[1] + ls[2] + ls[3];
    q = lq[0] + lq[1] + lq[2] + lq[3];

    const float mean = s * (1.0f / 1024.0f);
    const float var = q * (1.0f / 1024.0f) - mean * mean;
    const float rstd = rsqrtf(var + 1e-5f);

    const int c = t * 4;
    float4 g = *(const float4*)(gamma + c);
    float4 be = *(const float4*)(beta + c);
    float4 o;
    o.x = (v0 - mean) * rstd * g.x + be.x;
    o.y = (v1 - mean) * rstd * g.y + be.y;
    o.z = (v2 - mean) * rstd * g.z + be.z;
    o.w = (v3 - mean) * rstd * g.w + be.w;
    *(float4*)(out + base) = o;
}

extern "C" void kernel_launch(void* const* d_in, const int* in_sizes, int n_in,
                              void* d_out, int out_size, void* d_ws, size_t ws_size,
                              hipStream_t stream)
{
    const float* x     = (const float*)d_in[0];
    const float* Wq    = (const float*)d_in[1];
    const float* bq    = (const float*)d_in[2];
    const float* Wk    = (const float*)d_in[3];
    const float* bk    = (const float*)d_in[4];
    const float* Wv    = (const float*)d_in[5];
    const float* bv    = (const float*)d_in[6];
    const float* Wo    = (const float*)d_in[7];
    const float* bo    = (const float*)d_in[8];
    const float* gamma = (const float*)d_in[9];
    const float* beta  = (const float*)d_in[10];
    float* out = (float*)d_out;

    char* ws = (char*)d_ws;
    u8* x8  = (u8*)(ws + (size_t)0);          // 16 MB; reused as AO8 later
    u8* QK8 = (u8*)(ws + (size_t)16777216);   // 32 MB [16384,2048] Q||K
    u8* VT8 = (u8*)(ws + (size_t)50331648);   // 16 MB [1024,16384]
    u8* P8  = (u8*)(ws + (size_t)67108864);   // 32 MB [8,2048,2048]
    float* bqk = (float*)(ws + (size_t)100663296); // 8 KB bq||bk
    bf16* Sb = (bf16*)(ws + (size_t)104857600); // 64 MB scores; preLN reuse
    u8* Wq8 = (u8*)(ws + (size_t)176160768);  // 4 MB contiguous W{q,k,v,o}8
    u8* Wv8 = Wq8 + 2097152;
    u8* Wo8 = Wv8 + 1048576;
    u8* AO8 = x8;                              // x8 dead after projections

    // all casts + bias concat (1 launch)
    cast_all<<<10241, 256, 0, stream>>>(x, Wq, Wk, Wv, Wo, bq, bk,
                                        x8, Wq8, bqk);

    // QK8 = x8 @ [Wq8;Wk8]^T + bqk  (fp8 out, [16384,2048])
    gemm_f8<<<dim3(8, 64, 1), 512, 0, stream>>>(
        x8, 1024, 0, Wq8, 1024, 0, (void*)QK8, 2048, 0, bqk, 1, 1.0f, 1, 1024);
    // VT8 = Wv8@x8^T + bv(row)  [1024,16384] fp8
    gemm_f8<<<dim3(64, 4, 1), 512, 0, stream>>>(
        Wv8, 1024, 0, x8, 1024, 0, (void*)VT8, 16384, 0, bv, 2, 1.0f, 1, 1024);
    // scores (bf16) = Q@K^T / 32 per batch; Q = QK8[:, :1024], K = QK8[:,1024:]
    gemm_f8<<<dim3(8, 8, 8), 512, 0, stream>>>(
        QK8, 2048, 4194304, QK8 + 1024, 2048, 4194304, (void*)Sb, 2048, 4194304,
        nullptr, 0, 0.03125f, 0, 1024);
    // P8 = softmax(scores) * 256  (fp8)
    softmax_f8<<<16384, 256, 0, stream>>>(Sb, P8);
    // AO8 = (P8@VT8^T) * 16/256 -> stored AO = 16*AO_true (into x8 slot)
    gemm_f8<<<dim3(4, 8, 8), 512, 0, stream>>>(
        P8, 2048, 4194304, VT8, 16384, 2048, (void*)AO8, 1024, 2097152,
        nullptr, 0, 0.0625f, 1, 2048);
    // preLN (bf16, into Sb) = AO8@Wo8^T * (1/16) + bo
    gemm_f8<<<dim3(4, 64, 1), 512, 0, stream>>>(
        AO8, 1024, 0, Wo8, 1024, 0, (void*)Sb, 1024, 0, bo, 1, 0.0625f, 0, 1024);
    // out = LN(pre + x)
    ln_res<<<16384, 256, 0, stream>>>((const bf16*)Sb, x, gamma, beta, out);
}